// Round 2
// baseline (364.760 us; speedup 1.0000x reference)
//
#include <hip/hip_runtime.h>

// Problem constants (fixed by the reference file).
#define N_NODES 8192
#define DIM     256
#define NH      64
#define DEG     32
#define G       8      // nodes per block in QKV kernel (amortizes weight reads)

// Kernel A: QKV projection, G nodes per 64-thread block.
// Thread t owns output dim t for all G nodes and all 3 matrices.
// x-rows staged in LDS (f32, broadcast reads); W rows streamed as float4
// from L2 (each block reads the 192 KB of weights once -> ~200 MB L2 total).
__global__ __launch_bounds__(64) void qkv_kernel(
    const float* __restrict__ x,
    const float* __restrict__ Wq, const float* __restrict__ bq,
    const float* __restrict__ Wk, const float* __restrict__ bk,
    const float* __restrict__ Wv,
    float* __restrict__ Q, float* __restrict__ K, float* __restrict__ V)
{
    const int g0 = blockIdx.x * G;      // first node of this block
    const int t  = threadIdx.x;         // 0..63 = output dim

    __shared__ float xs[G * DIM];       // 8 KB

    // Stage G x-rows: G*DIM = 2048 floats = 512 float4; 8 per thread, coalesced.
    const float4* xin = (const float4*)(x + (size_t)g0 * DIM);
    float4* xs4 = (float4*)xs;
    #pragma unroll
    for (int c = 0; c < (G * DIM / 4) / 64; ++c)
        xs4[t + 64 * c] = xin[t + 64 * c];
    __syncthreads();

    const float4* wq = (const float4*)(Wq + t * DIM);
    const float4* wk = (const float4*)(Wk + t * DIM);
    const float4* wv = (const float4*)(Wv + t * DIM);

    float accq[G], acck[G], accv[G];
    #pragma unroll
    for (int m = 0; m < G; ++m) { accq[m] = 0.f; acck[m] = 0.f; accv[m] = 0.f; }

    for (int c = 0; c < DIM / 4; ++c) {         // 64 iterations
        const float4 aq = wq[c];
        const float4 ak = wk[c];
        const float4 av = wv[c];
        #pragma unroll
        for (int m = 0; m < G; ++m) {
            // wave-uniform address -> LDS broadcast, no bank conflicts
            const float4 xv = ((const float4*)(xs + m * DIM))[c];
            accq[m] += xv.x * aq.x + xv.y * aq.y + xv.z * aq.z + xv.w * aq.w;
            acck[m] += xv.x * ak.x + xv.y * ak.y + xv.z * ak.z + xv.w * ak.w;
            accv[m] += xv.x * av.x + xv.y * av.y + xv.z * av.z + xv.w * av.w;
        }
    }

    const float bqv = bq[t];
    const float bkv = bk[t];
    #pragma unroll
    for (int m = 0; m < G; ++m) {
        const int o = (g0 + m) * NH + t;        // coalesced per m
        Q[o] = accq[m] + bqv;
        K[o] = acck[m] + bkv;
        V[o] = accv[m];
    }
}

// Kernel B: sparse attention over the 32 neighbors of each node.
// One wave per node. Lanes 0..31: score for neighbor j = (Q_i . K_j + ek)/512
// (the reference's /H then /sqrt(H), H=64). 64-lane shuffle softmax
// (inactive lanes carry -1e30 -> exp == 0). Then all 64 lanes accumulate
// O[i][t] = sum_j p_j * V[nbr_j][t] (coalesced 256B per neighbor).
__global__ __launch_bounds__(64) void attn_kernel(
    const float* __restrict__ Q, const float* __restrict__ K,
    const float* __restrict__ V,
    const int* __restrict__ edge_dst,     // [E]; node i owns e = i*DEG .. i*DEG+DEG-1
    const int* __restrict__ edge_type,    // [E]
    const float* __restrict__ ektab,      // [NTYPES]
    float* __restrict__ out)              // [N, NH] f32
{
    const int i = blockIdx.x;
    const int t = threadIdx.x;            // 0..63

    __shared__ float qs[NH];
    __shared__ float ps[DEG];
    __shared__ int   ns[DEG];

    qs[t] = Q[i * NH + t];
    __syncthreads();

    float s = -1e30f;
    if (t < DEG) {
        const int e   = i * DEG + t;
        const int nbr = edge_dst[e];
        ns[t] = nbr;
        const float ek = ektab[edge_type[e]];
        const float4* kr = (const float4*)(K + (size_t)nbr * NH);
        const float4* q4 = (const float4*)qs;
        float acc = 0.f;
        #pragma unroll
        for (int d = 0; d < NH / 4; ++d) {
            const float4 kv = kr[d];
            const float4 qv = q4[d];      // uniform address -> broadcast
            acc += qv.x * kv.x + qv.y * kv.y + qv.z * kv.z + qv.w * kv.w;
        }
        s = (acc + ek) * (1.0f / 512.0f);   // /H then /sqrt(H): 64*8
    }

    // wave softmax across 64 lanes (lanes >= DEG contribute exp -> 0)
    float m = s;
    #pragma unroll
    for (int off = 32; off > 0; off >>= 1) m = fmaxf(m, __shfl_xor(m, off));
    float p = __expf(s - m);
    float l = p;
    #pragma unroll
    for (int off = 32; off > 0; off >>= 1) l += __shfl_xor(l, off);
    p /= l;

    if (t < DEG) ps[t] = p;
    __syncthreads();

    float o = 0.f;
    #pragma unroll 8
    for (int j = 0; j < DEG; ++j)
        o += ps[j] * V[(size_t)ns[j] * NH + t];

    out[i * NH + t] = o;
}

extern "C" void kernel_launch(void* const* d_in, const int* in_sizes, int n_in,
                              void* d_out, int out_size, void* d_ws, size_t ws_size,
                              hipStream_t stream) {
    // setup_inputs order (all floats are f32 per the reference):
    // 0:x [N,D]  1:adj [N,N] (UNUSED)  2:edge_index [2,E] i32
    // 3:edge_type [E] i32  4:Wq [H,D]  5:bq [H]  6:Wk  7:bk  8:Wv
    // 9:edge_k_table [16,1]
    const float* x     = (const float*)d_in[0];
    const int*   eidx  = (const int*)d_in[2];
    const int*   etyp  = (const int*)d_in[3];
    const float* Wq    = (const float*)d_in[4];
    const float* bq    = (const float*)d_in[5];
    const float* Wk    = (const float*)d_in[6];
    const float* bk    = (const float*)d_in[7];
    const float* Wv    = (const float*)d_in[8];
    const float* ektab = (const float*)d_in[9];
    float*       out   = (float*)d_out;

    const int E = in_sizes[2] / 2;        // 262144

    float* Q = (float*)d_ws;              // [N, NH] f32
    float* K = Q + (size_t)N_NODES * NH;
    float* V = K + (size_t)N_NODES * NH;  // total 6 MB of ws

    qkv_kernel<<<dim3(N_NODES / G), dim3(64), 0, stream>>>(x, Wq, bq, Wk, bk, Wv, Q, K, V);
    attn_kernel<<<dim3(N_NODES), dim3(64), 0, stream>>>(Q, K, V, eidx + E, etyp, ektab, out);
}